// Round 5
// baseline (254.470 us; speedup 1.0000x reference)
//
#include <hip/hip_runtime.h>
#include <hip/hip_bf16.h>

#define C 128
#define INV_SQRT2 0.7071067811865476f
#define NB 1024         // radix buckets (col >> 7); 782 used for N=100000
#define BS 128          // nodes per bucket
#define EPB 4096        // edges per partition block
#define CAP 4096        // max edges per bucket staged in LDS (mean ~2048)

typedef __attribute__((ext_vector_type(8))) short short8;
typedef __attribute__((ext_vector_type(4))) float f32x4;

__device__ inline ushort f2b(float f) {
    __hip_bfloat16 h = __float2bfloat16(f);
    return __builtin_bit_cast(ushort, h);
}

// ---------------- front kernel: bucket histogram | x->bf16 cast | weight pack ----------------

__global__ __launch_bounds__(512) void k_front(
    const int* __restrict__ col, int E, int* __restrict__ totals, int nblk,
    const float4* __restrict__ x, ushort* __restrict__ xb, int n4, int castBlocks,
    const float* __restrict__ w_res, const float* __restrict__ w_neigh,
    ushort* __restrict__ Bp)
{
    __shared__ int hist[NB];
    int b = blockIdx.x;
    int t = threadIdx.x;
    if (b < nblk) {
        // ---- histogram -> global totals ----
        hist[t] = 0; hist[t + 512] = 0;
        __syncthreads();
        int base = b * EPB;
        #pragma unroll
        for (int i = 0; i < EPB / 512; i++) {
            int e = base + i * 512 + t;
            if (e < E) atomicAdd(&hist[col[e] >> 7], 1);
        }
        __syncthreads();
        int h0 = hist[t], h1 = hist[t + 512];
        if (h0) atomicAdd(&totals[t], h0);
        if (h1) atomicAdd(&totals[t + 512], h1);
    } else if (b < nblk + castBlocks) {
        // ---- cast x -> bf16 ----
        int i = (b - nblk) * 512 + t;
        if (i < n4) {
            float4 v = x[i];
            ushort4 o;
            o.x = f2b(v.x); o.y = f2b(v.y); o.z = f2b(v.z); o.w = f2b(v.w);
            *(ushort4*)(xb + (size_t)i * 4) = o;
        }
    } else {
        // ---- weight normalize + pack into B-fragment layout ----
        int r = (b - nblk - castBlocks) * 8 + (t >> 6);   // 0..255
        int h = r >> 7;
        int i = r & 127;
        const float* w = h ? w_neigh : w_res;
        int lane = t & 63;
        float a = w[i * C + lane];
        float bb = w[i * C + lane + 64];
        float ss = a * a + bb * bb;
        #pragma unroll
        for (int off = 32; off > 0; off >>= 1) ss += __shfl_down(ss, off);
        ss = __shfl(ss, 0);
        float norm = sqrtf(ss);
        float denom = 1e-4f + norm * 0.08838834764831845f;   // eps + norm/sqrt(128)
        float scale = 1.0f / (denom * 11.313708498984761f);  // /denom /sqrt(128)
        int c1 = lane, c2 = lane + 64;
        Bp[(size_t)(h * 16 + (c1 >> 3)) * 1024 + i * 8 + (c1 & 7)] = f2b(a * scale);
        Bp[(size_t)(h * 16 + (c2 >> 3)) * 1024 + i * 8 + (c2 & 7)] = f2b(bb * scale);
    }
}

// ---------------- scan bucket totals -> bucketBase, init claim cursors ----------------

__global__ __launch_bounds__(NB) void k_scan_buckets(const int* __restrict__ totals,
                                                     int* __restrict__ bucketBase,
                                                     int* __restrict__ gcursor) {
    __shared__ int s[NB];
    int t = threadIdx.x;
    int v = totals[t];
    s[t] = v;
    __syncthreads();
    for (int off = 1; off < NB; off <<= 1) {
        int add = (t >= off) ? s[t - off] : 0;
        __syncthreads();
        s[t] += add;
        __syncthreads();
    }
    int base = s[t] - v;          // exclusive
    bucketBase[t] = base;
    gcursor[t] = base;
}

// ---------------- partition edges into bucket-contiguous records (dynamic claim) ----------------
// rec = ((col & 127) << 24) | row   (row < 2^24)

__global__ __launch_bounds__(512) void k_partition(
    const int* __restrict__ row, const int* __restrict__ col, int E,
    int* __restrict__ gcursor, unsigned int* __restrict__ recs)
{
    __shared__ int hist[NB];
    __shared__ int lbase[NB];
    int t = threadIdx.x;
    hist[t] = 0; hist[t + 512] = 0;
    __syncthreads();
    int base = blockIdx.x * EPB;
    #pragma unroll
    for (int i = 0; i < EPB / 512; i++) {
        int e = base + i * 512 + t;
        if (e < E) atomicAdd(&hist[col[e] >> 7], 1);
    }
    __syncthreads();
    #pragma unroll
    for (int k = 0; k < 2; k++) {
        int b = t + k * 512;
        int h = hist[b];
        lbase[b] = h ? atomicAdd(&gcursor[b], h) : 0;
    }
    __syncthreads();
    hist[t] = 0; hist[t + 512] = 0;   // reuse as rank
    __syncthreads();
    #pragma unroll
    for (int i = 0; i < EPB / 512; i++) {
        int e = base + i * 512 + t;
        if (e < E) {
            int c = col[e];
            int k = c >> 7;
            int p = atomicAdd(&hist[k], 1);
            recs[lbase[k] + p] = ((unsigned int)(c & 127) << 24) | (unsigned int)row[e];
        }
    }
}

// ---------------- fused bucket CSR + aggregation ----------------
// one block per 128-node bucket: sort recs into LDS index list, then
// aggregate: 8 waves x 16 nodes; 16 lanes/row (uint4 = 8 ch), 4 edge slots.

#define ACCUM(v) do { \
    acc[0] += __builtin_bit_cast(float, (v).x << 16); \
    acc[1] += __builtin_bit_cast(float, (v).x & 0xffff0000u); \
    acc[2] += __builtin_bit_cast(float, (v).y << 16); \
    acc[3] += __builtin_bit_cast(float, (v).y & 0xffff0000u); \
    acc[4] += __builtin_bit_cast(float, (v).z << 16); \
    acc[5] += __builtin_bit_cast(float, (v).z & 0xffff0000u); \
    acc[6] += __builtin_bit_cast(float, (v).w << 16); \
    acc[7] += __builtin_bit_cast(float, (v).w & 0xffff0000u); \
} while (0)

__global__ __launch_bounds__(512) void k_bucket_agg(
    const unsigned int* __restrict__ recs, const int* __restrict__ bucketBase,
    const int* __restrict__ totals, const ushort* __restrict__ xb,
    ushort* __restrict__ aggb, int* __restrict__ deg, int N)
{
    __shared__ int lidx[CAP];
    __shared__ int shist[BS];
    __shared__ int sexcl[BS];
    __shared__ int scur[BS];
    int k = blockIdx.x;
    int t = threadIdx.x;
    int base = bucketBase[k];
    int cnt  = totals[k];
    if (cnt > CAP) cnt = CAP;
    if (t < BS) shist[t] = 0;
    __syncthreads();
    for (int i = t; i < cnt; i += 512)
        atomicAdd(&shist[recs[base + i] >> 24], 1);
    __syncthreads();
    int v = (t < BS) ? shist[t] : 0;
    if (t < BS) sexcl[t] = v;
    __syncthreads();
    for (int off = 1; off < BS; off <<= 1) {
        int add = (t < BS && t >= off) ? sexcl[t - off] : 0;
        __syncthreads();
        if (t < BS) sexcl[t] += add;
        __syncthreads();
    }
    if (t < BS) {
        int ex = sexcl[t] - v;    // exclusive offset within bucket
        sexcl[t] = ex;
        scur[t] = ex;
        int node = k * BS + t;
        if (node < N) deg[node] = v;
    }
    __syncthreads();
    for (int i = t; i < cnt; i += 512) {
        unsigned int r = recs[base + i];
        int c = r >> 24;
        int p = atomicAdd(&scur[c], 1);
        lidx[p] = (int)(r & 0xFFFFFF);
    }
    __syncthreads();

    // ---- aggregation: wave handles 16 nodes ----
    int wave = t >> 6;
    int lane = t & 63;
    int sub  = lane >> 4;       // edge slot 0..3
    int cl   = lane & 15;       // channel block: channels cl*8 .. cl*8+7
    int lnEnd = wave * 16 + 16;
    for (int ln = wave * 16; ln < lnEnd; ln++) {
        int node = k * BS + ln;
        if (node >= N) break;
        int s0 = sexcl[ln];
        int d  = shist[ln];
        float acc[8];
        #pragma unroll
        for (int i = 0; i < 8; i++) acc[i] = 0.f;
        for (int j = 0; j < d; j += 8) {
            int jj0 = j + sub;
            int jj1 = j + 4 + sub;
            int i0 = lidx[s0 + (jj0 < d ? jj0 : d - 1)];
            int i1 = lidx[s0 + (jj1 < d ? jj1 : d - 1)];
            uint4 va = *(const uint4*)(xb + ((size_t)i0 << 7) + (cl << 3));
            uint4 vb = *(const uint4*)(xb + ((size_t)i1 << 7) + (cl << 3));
            if (jj0 >= d) va = make_uint4(0, 0, 0, 0);
            if (jj1 >= d) vb = make_uint4(0, 0, 0, 0);
            ACCUM(va);
            ACCUM(vb);
        }
        #pragma unroll
        for (int i = 0; i < 8; i++) {
            acc[i] += __shfl_xor(acc[i], 16);
            acc[i] += __shfl_xor(acc[i], 32);
        }
        float dd = (d > 0) ? rsqrtf((float)d) : 0.f;
        if (lane < 16) {
            uint4 o;
            o.x = (uint)f2b(acc[0] * dd) | ((uint)f2b(acc[1] * dd) << 16);
            o.y = (uint)f2b(acc[2] * dd) | ((uint)f2b(acc[3] * dd) << 16);
            o.z = (uint)f2b(acc[4] * dd) | ((uint)f2b(acc[5] * dd) << 16);
            o.w = (uint)f2b(acc[6] * dd) | ((uint)f2b(acc[7] * dd) << 16);
            *(uint4*)(aggb + ((size_t)node << 7) + (cl << 3)) = o;
        }
    }
}

// ---------------- MFMA GEMM: out = mask * ([xb | aggb] @ [Wres|Wneigh]^T) ----------------

__global__ __launch_bounds__(256) void k_gemm_mfma(
    const ushort* __restrict__ xb, const ushort* __restrict__ aggb,
    const ushort* __restrict__ Bp, const int* __restrict__ deg,
    float* __restrict__ out, int N)
{
    int wave = threadIdx.x >> 6;
    int lane = threadIdx.x & 63;
    int quad = lane >> 4;
    int l16  = lane & 15;
    int wm = wave & 1, wn = wave >> 1;
    long n0 = (long)blockIdx.x * 128 + wm * 64;
    int  c0 = wn * 64;

    f32x4 acc[4][4];
    #pragma unroll
    for (int mt = 0; mt < 4; mt++)
        #pragma unroll
        for (int nt = 0; nt < 4; nt++)
            acc[mt][nt] = (f32x4){0.f, 0.f, 0.f, 0.f};

    #pragma unroll
    for (int kk = 0; kk < 8; kk++) {
        const ushort* A = (kk < 4) ? xb : aggb;
        int k0 = (kk & 3) * 32;
        short8 af[4], bf[4];
        #pragma unroll
        for (int mt = 0; mt < 4; mt++) {
            long rrow = n0 + mt * 16 + l16;
            if (rrow >= N) rrow = N - 1;   // clamp; garbage rows never stored
            af[mt] = *(const short8*)(A + rrow * C + k0 + quad * 8);
        }
        #pragma unroll
        for (int nt = 0; nt < 4; nt++) {
            int n = c0 + nt * 16 + l16;
            bf[nt] = *(const short8*)(Bp + ((size_t)(kk * 4 + quad) * 128 + n) * 8);
        }
        #pragma unroll
        for (int mt = 0; mt < 4; mt++)
            #pragma unroll
            for (int nt = 0; nt < 4; nt++)
                acc[mt][nt] = __builtin_amdgcn_mfma_f32_16x16x32_bf16(
                    af[mt], bf[nt], acc[mt][nt], 0, 0, 0);
    }

    #pragma unroll
    for (int mt = 0; mt < 4; mt++) {
        long rbase = n0 + mt * 16 + quad * 4;
        #pragma unroll
        for (int r = 0; r < 4; r++) {
            long row = rbase + r;
            if (row < N) {
                float sc = (deg[row] > 0) ? INV_SQRT2 : 1.0f;
                float* o = out + row * C + c0 + l16;
                #pragma unroll
                for (int nt = 0; nt < 4; nt++)
                    __builtin_nontemporal_store(acc[mt][nt][r] * sc, &o[nt * 16]);
            }
        }
    }
}

// ---------------- host ----------------

extern "C" void kernel_launch(void* const* d_in, const int* in_sizes, int n_in,
                              void* d_out, int out_size, void* d_ws, size_t ws_size,
                              hipStream_t stream) {
    const float* x       = (const float*)d_in[0];
    const int*   eidx    = (const int*)d_in[1];
    const float* w_neigh = (const float*)d_in[2];
    const float* w_res   = (const float*)d_in[3];
    float* out = (float*)d_out;

    int N = in_sizes[0] / C;
    int E = in_sizes[1] / 2;
    const int* row = eidx;        // edge_index[0] = source
    const int* col = eidx + E;    // edge_index[1] = target

    char* ws = (char*)d_ws;
    size_t off = 0;
    auto alloc = [&](size_t bytes) {
        size_t o = off;
        off += (bytes + 511) & ~(size_t)511;
        return o;
    };
    int nblk = (E + EPB - 1) / EPB;   // 391 for E=1.6M

    int*    totals     = (int*)(ws + alloc(NB * 4));
    int*    bucketBase = (int*)(ws + alloc(NB * 4));
    int*    gcursor    = (int*)(ws + alloc(NB * 4));
    int*    deg        = (int*)(ws + alloc((size_t)N * 4));
    unsigned int* recs = (unsigned int*)(ws + alloc((size_t)E * 4));
    ushort* Bp         = (ushort*)(ws + alloc((size_t)32 * 1024 * 2));
    ushort* xb         = (ushort*)(ws + alloc((size_t)N * C * 2));
    ushort* aggb       = (ushort*)(ws + alloc((size_t)N * C * 2));
    (void)ws_size;

    hipMemsetAsync(totals, 0, NB * 4, stream);

    int nbuckets = (N + BS - 1) / BS;    // 782
    int n4 = N * C / 4;
    int castBlocks = (n4 + 511) / 512;

    k_front<<<nblk + castBlocks + 32, 512, 0, stream>>>(
        col, E, totals, nblk, (const float4*)x, xb, n4, castBlocks,
        w_res, w_neigh, Bp);
    k_scan_buckets<<<1, NB, 0, stream>>>(totals, bucketBase, gcursor);
    k_partition<<<nblk, 512, 0, stream>>>(row, col, E, gcursor, recs);
    k_bucket_agg<<<nbuckets, 512, 0, stream>>>(recs, bucketBase, totals, xb, aggb, deg, N);
    k_gemm_mfma<<<(N + 127) / 128, 256, 0, stream>>>(xb, aggb, Bp, deg, out, N);
}

// Round 7
// 222.824 us; speedup vs baseline: 1.1420x; 1.1420x over previous
//
#include <hip/hip_runtime.h>
#include <hip/hip_bf16.h>

#define C 128
#define INV_SQRT2 0.7071067811865476f
#define NB 1024         // radix buckets (col >> 7); 782 used for N=100000
#define BS 128          // nodes per bucket
#define EPB 4096        // edges per partition block
#define CAPB 2560       // fixed record capacity per bucket (mean 2046, +11 sigma)
#define AGS 68          // sAgg row stride in uints: 64 data (128ch bf16) + 4 pad

typedef __attribute__((ext_vector_type(8))) short short8;
typedef __attribute__((ext_vector_type(4))) float f32x4;

__device__ inline ushort f2b(float f) {
    __hip_bfloat16 h = __float2bfloat16(f);
    return __builtin_bit_cast(ushort, h);
}

// ---------------- front kernel: partition | x->bf16 cast | weight pack ----------------
// partition uses direct-claim: gcursor starts at 0, blocks claim contiguous
// ranges per bucket; recs live at fixed per-bucket capacity CAPB.

__global__ __launch_bounds__(512) void k_front(
    const int* __restrict__ row, const int* __restrict__ col, int E, int nblk,
    int* __restrict__ gcursor, unsigned int* __restrict__ recs,
    const float4* __restrict__ x, ushort* __restrict__ xb, int n4, int castBlocks,
    const float* __restrict__ w_res, const float* __restrict__ w_neigh,
    ushort* __restrict__ Bp)
{
    __shared__ int hist[NB];
    __shared__ int lbase[NB];
    int b = blockIdx.x;
    int t = threadIdx.x;
    if (b < nblk) {
        // ---- partition: hist pass ----
        hist[t] = 0; hist[t + 512] = 0;
        __syncthreads();
        int base = b * EPB;
        #pragma unroll
        for (int i = 0; i < EPB / 512; i++) {
            int e = base + i * 512 + t;
            if (e < E) atomicAdd(&hist[col[e] >> 7], 1);
        }
        __syncthreads();
        #pragma unroll
        for (int kx = 0; kx < 2; kx++) {
            int bb = t + kx * 512;
            int h = hist[bb];
            lbase[bb] = h ? atomicAdd(&gcursor[bb], h) : 0;
        }
        __syncthreads();
        hist[t] = 0; hist[t + 512] = 0;   // reuse as rank
        __syncthreads();
        #pragma unroll
        for (int i = 0; i < EPB / 512; i++) {
            int e = base + i * 512 + t;
            if (e < E) {
                int c = col[e];
                int kk = c >> 7;
                int p = atomicAdd(&hist[kk], 1) + lbase[kk];
                if (p < CAPB)
                    recs[(size_t)kk * CAPB + p] =
                        ((unsigned int)(c & 127) << 24) | (unsigned int)row[e];
            }
        }
    } else if (b < nblk + castBlocks) {
        // ---- cast x -> bf16 ----
        int i = (b - nblk) * 512 + t;
        if (i < n4) {
            float4 v = x[i];
            ushort4 o;
            o.x = f2b(v.x); o.y = f2b(v.y); o.z = f2b(v.z); o.w = f2b(v.w);
            *(ushort4*)(xb + (size_t)i * 4) = o;
        }
    } else {
        // ---- weight normalize + pack into B-fragment layout ----
        int r = (b - nblk - castBlocks) * 8 + (t >> 6);   // 0..255
        int h = r >> 7;
        int i = r & 127;
        const float* w = h ? w_neigh : w_res;
        int lane = t & 63;
        float a = w[i * C + lane];
        float bb = w[i * C + lane + 64];
        float ss = a * a + bb * bb;
        #pragma unroll
        for (int off = 32; off > 0; off >>= 1) ss += __shfl_down(ss, off);
        ss = __shfl(ss, 0);
        float norm = sqrtf(ss);
        float denom = 1e-4f + norm * 0.08838834764831845f;   // eps + norm/sqrt(128)
        float scale = 1.0f / (denom * 11.313708498984761f);  // /denom /sqrt(128)
        int c1 = lane, c2 = lane + 64;
        Bp[(size_t)(h * 16 + (c1 >> 3)) * 1024 + i * 8 + (c1 & 7)] = f2b(a * scale);
        Bp[(size_t)(h * 16 + (c2 >> 3)) * 1024 + i * 8 + (c2 & 7)] = f2b(bb * scale);
    }
}

// ---------------- fused: bucket sort -> gather-aggregate -> MFMA GEMM -> out ----------------
// one block per 128-node bucket, 512 threads (8 waves).
// phase a: sort recs into LDS lidx (per-node runs) — single-wave shfl scan.
// phase b: R4-style gather: wave owns 16 nodes sequentially; 4 edge slots x
//          16 lanes x uint4; register accum; agg row -> LDS bf16 (64 uints + 4 pad).
// phase c: out[128 nodes] = mask * ([xb_tile | sAgg] @ Bp), stored directly.

#define ACCUM(v) do { \
    acc[0] += __builtin_bit_cast(float, (v).x << 16); \
    acc[1] += __builtin_bit_cast(float, (v).x & 0xffff0000u); \
    acc[2] += __builtin_bit_cast(float, (v).y << 16); \
    acc[3] += __builtin_bit_cast(float, (v).y & 0xffff0000u); \
    acc[4] += __builtin_bit_cast(float, (v).z << 16); \
    acc[5] += __builtin_bit_cast(float, (v).z & 0xffff0000u); \
    acc[6] += __builtin_bit_cast(float, (v).w << 16); \
    acc[7] += __builtin_bit_cast(float, (v).w & 0xffff0000u); \
} while (0)

__global__ __launch_bounds__(512, 4) void k_fused(
    const unsigned int* __restrict__ recs, const int* __restrict__ gcursor,
    const ushort* __restrict__ xb, const ushort* __restrict__ Bp,
    float* __restrict__ out, int N)
{
    __shared__ int lidx[CAPB];          // 10240 B
    __shared__ int shist[BS];
    __shared__ int sexcl[BS];
    __shared__ int scur[BS];
    __shared__ uint sAgg[BS * AGS];     // 34816 B

    int k = blockIdx.x;
    int t = threadIdx.x;
    int cnt = gcursor[k];
    if (cnt > CAPB) cnt = CAPB;
    const unsigned int* rb = recs + (size_t)k * CAPB;

    // ---- phase a: per-node counts + offsets + scatter to lidx ----
    if (t < BS) shist[t] = 0;
    __syncthreads();
    for (int i = t; i < cnt; i += 512)
        atomicAdd(&shist[rb[i] >> 24], 1);
    __syncthreads();
    if (t < 64) {
        int a = shist[t], b = shist[t + 64];
        int ia = a, ib = b;
        #pragma unroll
        for (int off = 1; off < 64; off <<= 1) {
            int ya = __shfl_up(ia, off);
            int yb = __shfl_up(ib, off);
            if (t >= off) { ia += ya; ib += yb; }
        }
        int tot0 = __shfl(ia, 63);
        int e0 = ia - a;
        int e1 = ib - b + tot0;
        sexcl[t] = e0;      scur[t] = e0;
        sexcl[t + 64] = e1; scur[t + 64] = e1;
    }
    __syncthreads();
    for (int i = t; i < cnt; i += 512) {
        unsigned int r = rb[i];
        int c = r >> 24;
        int p = atomicAdd(&scur[c], 1);
        lidx[p] = (int)(r & 0xFFFFFF);
    }
    __syncthreads();

    // ---- phase b: gather-aggregate, write bf16 rows to sAgg ----
    int lane = t & 63;
    int wave = t >> 6;
    int s  = lane >> 4;     // edge slot 0..3
    int cl = lane & 15;     // channel block: channels cl*8 .. cl*8+7
    #pragma unroll 1
    for (int ln = wave * 16; ln < wave * 16 + 16; ln++) {
        int s0 = sexcl[ln];
        int d  = shist[ln];
        float acc[8];
        #pragma unroll
        for (int i = 0; i < 8; i++) acc[i] = 0.f;
        for (int j = 0; j < d; j += 8) {
            int j0 = j + s, j1 = j + 4 + s;
            int i0 = lidx[s0 + (j0 < d ? j0 : d - 1)];
            int i1 = lidx[s0 + (j1 < d ? j1 : d - 1)];
            uint4 va = *(const uint4*)(xb + ((size_t)i0 << 7) + (cl << 3));
            uint4 vb = *(const uint4*)(xb + ((size_t)i1 << 7) + (cl << 3));
            if (j0 >= d) va = make_uint4(0, 0, 0, 0);
            if (j1 >= d) vb = make_uint4(0, 0, 0, 0);
            ACCUM(va);
            ACCUM(vb);
        }
        #pragma unroll
        for (int i = 0; i < 8; i++) {
            acc[i] += __shfl_xor(acc[i], 16);
            acc[i] += __shfl_xor(acc[i], 32);
        }
        float dd = (d > 0) ? rsqrtf((float)d) : 0.f;
        if (lane < 16) {
            uint4 o;
            o.x = (uint)f2b(acc[0] * dd) | ((uint)f2b(acc[1] * dd) << 16);
            o.y = (uint)f2b(acc[2] * dd) | ((uint)f2b(acc[3] * dd) << 16);
            o.z = (uint)f2b(acc[4] * dd) | ((uint)f2b(acc[5] * dd) << 16);
            o.w = (uint)f2b(acc[6] * dd) | ((uint)f2b(acc[7] * dd) << 16);
            *(uint4*)&sAgg[ln * AGS + cl * 4] = o;
        }
    }
    __syncthreads();

    // ---- phase c: GEMM. wave w: rows w*16..w*16+15, all 128 cols ----
    int quad = lane >> 4;
    int l16  = lane & 15;
    long gbase = (long)k * BS;
    int arow = wave * 16 + l16;
    long garow = gbase + arow;
    if (garow >= N) garow = N - 1;   // clamp; garbage rows never stored

    f32x4 oacc[8];
    #pragma unroll
    for (int nt = 0; nt < 8; nt++) oacc[nt] = (f32x4){0.f, 0.f, 0.f, 0.f};

    #pragma unroll
    for (int kk = 0; kk < 8; kk++) {
        short8 af;
        if (kk < 4) {
            af = *(const short8*)(xb + garow * C + kk * 32 + quad * 8);
        } else {
            af = *(const short8*)&sAgg[arow * AGS + (kk - 4) * 16 + quad * 4];
        }
        #pragma unroll
        for (int nt = 0; nt < 8; nt++) {
            short8 bf = *(const short8*)(Bp +
                ((size_t)((kk * 4 + quad) * 128) + nt * 16 + l16) * 8);
            oacc[nt] = __builtin_amdgcn_mfma_f32_16x16x32_bf16(af, bf, oacc[nt], 0, 0, 0);
        }
    }

    #pragma unroll
    for (int r2 = 0; r2 < 4; r2++) {
        int rl = wave * 16 + quad * 4 + r2;
        long rowg = gbase + rl;
        if (rowg < N) {
            float sc = (shist[rl] > 0) ? INV_SQRT2 : 1.0f;
            float* o = out + rowg * C + l16;
            #pragma unroll
            for (int nt = 0; nt < 8; nt++)
                __builtin_nontemporal_store(oacc[nt][r2] * sc, &o[nt * 16]);
        }
    }
}

// ---------------- host ----------------

extern "C" void kernel_launch(void* const* d_in, const int* in_sizes, int n_in,
                              void* d_out, int out_size, void* d_ws, size_t ws_size,
                              hipStream_t stream) {
    const float* x       = (const float*)d_in[0];
    const int*   eidx    = (const int*)d_in[1];
    const float* w_neigh = (const float*)d_in[2];
    const float* w_res   = (const float*)d_in[3];
    float* out = (float*)d_out;

    int N = in_sizes[0] / C;
    int E = in_sizes[1] / 2;
    const int* row = eidx;        // edge_index[0] = source
    const int* col = eidx + E;    // edge_index[1] = target

    char* ws = (char*)d_ws;
    size_t off = 0;
    auto alloc = [&](size_t bytes) {
        size_t o = off;
        off += (bytes + 511) & ~(size_t)511;
        return o;
    };
    int nblk = (E + EPB - 1) / EPB;   // 391 for E=1.6M

    int*    gcursor    = (int*)(ws + alloc(NB * 4));
    unsigned int* recs = (unsigned int*)(ws + alloc((size_t)NB * CAPB * 4));
    ushort* Bp         = (ushort*)(ws + alloc((size_t)32 * 1024 * 2));
    ushort* xb         = (ushort*)(ws + alloc((size_t)N * C * 2 + 65536));
    (void)ws_size;

    hipMemsetAsync(gcursor, 0, NB * 4, stream);

    int nbuckets = (N + BS - 1) / BS;    // 782
    int n4 = N * C / 4;
    int castBlocks = (n4 + 511) / 512;

    k_front<<<nblk + castBlocks + 32, 512, 0, stream>>>(
        row, col, E, nblk, gcursor, recs,
        (const float4*)x, xb, n4, castBlocks, w_res, w_neigh, Bp);
    k_fused<<<nbuckets, 512, 0, stream>>>(recs, gcursor, xb, Bp, out, N);
}